// Round 6
// baseline (37.014 us; speedup 1.0000x reference)
//
#include <hip/hip_runtime.h>
#include <math.h>

// Problem constants
#define Dq 512
#define Vq 50257
#define Kq 100
#define KP 112              // K padded to 7*16
#define NORM_TERM 10.8249051f   // log(50257)
#define LOGK 4.6051702f         // log(100)
#define NBLK 1024           // 16384 positions / 16 per block

typedef __attribute__((ext_vector_type(8))) short short8;
typedef __attribute__((ext_vector_type(4))) float floatx4;
typedef __attribute__((ext_vector_type(4))) unsigned short ushort4v;
typedef __attribute__((ext_vector_type(8))) unsigned short ushort8v;

__device__ __forceinline__ unsigned short f2bf(float f) {
    union { float f; unsigned u; } v; v.f = f;
    unsigned r = v.u + 0x7FFFu + ((v.u >> 16) & 1u);   // RNE
    return (unsigned short)(r >> 16);
}

__device__ __forceinline__ float log_sigmoid(float x) {
    return fminf(x, 0.f) - __logf(1.f + __expf(-fabsf(x)));
}

// Gather + convert noise embedding rows to bf16 [112][512], zero-padded.
__global__ void prep_noise(const float* __restrict__ emb_w,
                           const float* __restrict__ emb_b,
                           const float* __restrict__ lpn,
                           const int* __restrict__ ns,
                           unsigned short* __restrict__ nB,
                           float* __restrict__ nAdj) {
    int k = blockIdx.x;     // 0..111
    int t = threadIdx.x;    // 0..127
    if (k < Kq) {
        int row = ns[k];
        floatx4 v = ((const floatx4*)(emb_w + (size_t)row * Dq))[t];
        ushort4v o;
        o.x = f2bf(v.x); o.y = f2bf(v.y); o.z = f2bf(v.z); o.w = f2bf(v.w);
        ((ushort4v*)(nB + (size_t)k * Dq))[t] = o;
        if (t == 0) nAdj[k] = emb_b[row] - NORM_TERM - lpn[row] - LOGK;
    } else {
        ushort4v z; z.x = 0; z.y = 0; z.z = 0; z.w = 0;
        ((ushort4v*)(nB + (size_t)k * Dq))[t] = z;
        if (t == 0) nAdj[k] = 0.f;
    }
}

// Block = 8 waves = 16 positions (512 threads, 8 waves/SIMD => 32 waves/CU).
// Stage 16 input rows once to LDS bf16 (XOR-swizzled). ONE barrier total.
// Wave w in 0..6: noise k-tile w (full-D, wave-private accumulator).
// Wave 7: target tile full-D; diagonal extracted in-register (no exchange).
// Each wave shfl-reduces and writes partials[bid*8+w]; no tail barriers.
__global__ __launch_bounds__(512, 8) void nce_main(
    const float* __restrict__ input,     // [16384][512]
    const float* __restrict__ emb_w,     // [V][512]
    const float* __restrict__ emb_b,     // [V]
    const float* __restrict__ lpn,       // [V]
    const int* __restrict__ target,      // [16384]
    const unsigned short* __restrict__ nB,   // [112][512] bf16
    const float* __restrict__ nAdj,          // [112]
    float* __restrict__ partials)            // [8192]
{
    __shared__ unsigned short A_lds[16 * 512];  // byte: row*1024 + (2c ^ ((row&7)<<4))

    int tid  = threadIdx.x;
    int lane = tid & 63;
    int w    = tid >> 6;            // 0..7
    int pos0 = (int)blockIdx.x * 16;
    int r16  = lane & 15;
    int g4   = lane >> 4;

    // ---- Stage 16 input rows -> LDS bf16 (each wave 2 rows, 32B/lane x2) ----
    {
        int half = g4 >> 1;                   // 0/1: which of the wave's 2 rows
        int sub  = g4 & 1;                    // 0/1: column half-group
        int row  = w * 2 + half;              // 0..15
        const float* src = input + (size_t)(pos0 + row) * Dq;
        char* base = (char*)A_lds + row * 1024;
        int sw = (row & 7) << 4;
#pragma unroll
        for (int j = 0; j < 2; ++j) {
            int c = r16 * 8 + sub * 128 + j * 256;   // float col
            floatx4 x0 = *(const floatx4*)(src + c);
            floatx4 x1 = *(const floatx4*)(src + c + 4);
            ushort8v o;
            o[0] = f2bf(x0.x); o[1] = f2bf(x0.y); o[2] = f2bf(x0.z); o[3] = f2bf(x0.w);
            o[4] = f2bf(x1.x); o[5] = f2bf(x1.y); o[6] = f2bf(x1.z); o[7] = f2bf(x1.w);
            *(ushort8v*)(base + ((c * 2) ^ sw)) = o;
        }
    }
    __syncthreads();

    const char* abase = (const char*)A_lds + r16 * 1024;
    int asw = (r16 & 7) << 4;

    float contrib = 0.f;

    if (w < 7) {
        // ---- Noise k-tile w: 16 MFMAs over full D ----
        const unsigned short* b0 = nB + (size_t)(w * 16 + r16) * Dq + g4 * 8;
        floatx4 acc = {0.f, 0.f, 0.f, 0.f};
#pragma unroll
        for (int dt = 0; dt < 16; ++dt) {
            short8 a = *(const short8*)(abase + ((dt * 64 + g4 * 16) ^ asw));
            short8 f = *(const short8*)(b0 + dt * 32);
            acc = __builtin_amdgcn_mfma_f32_16x16x32_bf16(a, f, acc, 0, 0, 0);
        }
        int k = w * 16 + r16;
        if (k < Kq) {
            float adj = nAdj[k];
#pragma unroll
            for (int r = 0; r < 4; ++r)
                contrib += log_sigmoid(-(acc[r] + adj));
        }
    } else {
        // ---- Target tile: full-D, diag in-register ----
        int tgt = target[pos0 + r16];
        const float* trow = emb_w + (size_t)tgt * Dq + g4 * 8;
        floatx4 accT = {0.f, 0.f, 0.f, 0.f};
#pragma unroll
        for (int dt = 0; dt < 16; ++dt) {
            floatx4 t0 = *(const floatx4*)(trow + dt * 32);
            floatx4 t1 = *(const floatx4*)(trow + dt * 32 + 4);
            short8 a = *(const short8*)(abase + ((dt * 64 + g4 * 16) ^ asw));
            short8 ft;
            ft[0] = (short)f2bf(t0.x); ft[1] = (short)f2bf(t0.y);
            ft[2] = (short)f2bf(t0.z); ft[3] = (short)f2bf(t0.w);
            ft[4] = (short)f2bf(t1.x); ft[5] = (short)f2bf(t1.y);
            ft[6] = (short)f2bf(t1.z); ft[7] = (short)f2bf(t1.w);
            accT = __builtin_amdgcn_mfma_f32_16x16x32_bf16(a, ft, accT, 0, 0, 0);
        }
        // D[row=g4*4+reg][col=r16]; diag of position r16 lives at g4==r16>>2
        if ((r16 >> 2) == g4) {
            float xt = accT[r16 & 3] + emb_b[tgt] - NORM_TERM - lpn[tgt] - LOGK;
            contrib += log_sigmoid(xt);
        }
    }

#pragma unroll
    for (int off = 32; off >= 1; off >>= 1)
        contrib += __shfl_xor(contrib, off);
    if (lane == 0) partials[(size_t)blockIdx.x * 8 + w] = contrib;
}

// Deterministic per-batch reduction: 64 batches x 128 partials each.
__global__ void finalize(const float* __restrict__ partials,
                         float* __restrict__ out) {
    __shared__ float s8[64][9];        // padded
    int t = threadIdx.x;               // 0..511
    int b = t >> 3, q = t & 7;
    float s = 0.f;
#pragma unroll
    for (int i = 0; i < 16; ++i) s += partials[b * 128 + q * 16 + i];
    s8[b][q] = s;
    __syncthreads();
    if (t < 64) {
        float r = 0.f;
#pragma unroll
        for (int i = 0; i < 8; ++i) r += s8[t][i];
        out[t] = r;
    }
}

extern "C" void kernel_launch(void* const* d_in, const int* in_sizes, int n_in,
                              void* d_out, int out_size, void* d_ws, size_t ws_size,
                              hipStream_t stream) {
    const float* input = (const float*)d_in[0];
    const float* emb_w = (const float*)d_in[1];
    const float* emb_b = (const float*)d_in[2];
    const float* lpn   = (const float*)d_in[3];
    const int*   tgt   = (const int*)d_in[4];
    const int*   ns    = (const int*)d_in[5];
    float* out = (float*)d_out;

    // ws layout: [0,114688) noise bf16; [114688,115200) nAdj(+pad);
    // [115200,147968) partials[8192].
    unsigned short* nB  = (unsigned short*)d_ws;
    float* nAdj     = (float*)((char*)d_ws + (size_t)KP * Dq * 2);
    float* partials = (float*)((char*)d_ws + (size_t)KP * Dq * 2 + 512);

    prep_noise<<<KP, 128, 0, stream>>>(emb_w, emb_b, lpn, ns, nB, nAdj);
    nce_main<<<NBLK, 512, 0, stream>>>(input, emb_w, emb_b, lpn, tgt, nB, nAdj,
                                       partials);
    finalize<<<1, 512, 0, stream>>>(partials, out);
}